// Round 3
// baseline (384.017 us; speedup 1.0000x reference)
//
#include <hip/hip_runtime.h>
#include <hip/hip_fp16.h>

#define CHUNK 1024
#define NBKT 8     // per-node atomic-counter buckets
#define SPAN 128   // max node-span of a 256-edge CSR chunk handled in LDS

typedef _Float16 half8 __attribute__((ext_vector_type(8)));
typedef float floatx4 __attribute__((ext_vector_type(4)));

__device__ __forceinline__ unsigned int pack2(float a, float b) {
    __half2 h = __floats2half2_rn(a, b);
    return *(unsigned int*)&h;
}

// ===========================================================================
// rank: per-edge slot within (src,bucket) sub-segment. deg is [N][NBKT];
// bucket = (e>>8)&7 so concurrently-running blocks hit different counters.
// ===========================================================================
__global__ __launch_bounds__(256) void rank_cvt(
    const int* __restrict__ ei, int* __restrict__ deg,
    unsigned short* __restrict__ r, int E)
{
    int e = blockIdx.x * 256 + threadIdx.x;
    if (e >= E) return;
    int bkt = (e >> 8) & (NBKT - 1);
    r[e] = (unsigned short)atomicAdd(&deg[(size_t)ei[e] * NBKT + bkt], 1);
}

__global__ __launch_bounds__(256) void scan_chunk_sums(
    const int* __restrict__ v, int* __restrict__ csum, int N)
{
    __shared__ int s[256];
    int base = blockIdx.x * CHUNK;
    int t = threadIdx.x;
    int acc = 0;
    #pragma unroll
    for (int i = 0; i < CHUNK / 256; ++i) {
        int idx = base + t + i * 256;
        if (idx < N) acc += v[idx];
    }
    s[t] = acc; __syncthreads();
    for (int o = 128; o > 0; o >>= 1) {
        if (t < o) s[t] += s[t + o];
        __syncthreads();
    }
    if (t == 0) csum[blockIdx.x] = s[0];
}

__global__ __launch_bounds__(256) void scan_chunk_off(
    const int* __restrict__ csum, int* __restrict__ coff, int nch)
{
    __shared__ int s[256];
    __shared__ int carry;
    int t = threadIdx.x;
    if (t == 0) carry = 0;
    __syncthreads();
    for (int base = 0; base < nch; base += 256) {
        int v = (base + t < nch) ? csum[base + t] : 0;
        s[t] = v; __syncthreads();
        for (int o = 1; o < 256; o <<= 1) {
            int add = (t >= o) ? s[t - o] : 0;
            __syncthreads();
            s[t] += add;
            __syncthreads();
        }
        int excl = carry + (t > 0 ? s[t - 1] : 0);
        if (base + t < nch) coff[base + t] = excl;
        __syncthreads();
        if (t == 0) carry += s[255];
        __syncthreads();
    }
}

__global__ __launch_bounds__(256) void scan_within_excl(
    const int* __restrict__ deg, int* __restrict__ pos,
    const int* __restrict__ coff, int N)
{
    __shared__ int s[256];
    int t = threadIdx.x;
    int base = blockIdx.x * CHUNK + t * 4;
    int v0 = 0, v1 = 0, v2 = 0, v3 = 0;
    if (base + 0 < N) v0 = deg[base + 0];
    if (base + 1 < N) v1 = deg[base + 1];
    if (base + 2 < N) v2 = deg[base + 2];
    if (base + 3 < N) v3 = deg[base + 3];
    s[t] = v0 + v1 + v2 + v3;
    __syncthreads();
    for (int o = 1; o < 256; o <<= 1) {
        int add = (t >= o) ? s[t - o] : 0;
        __syncthreads();
        s[t] += add;
        __syncthreads();
    }
    int run = coff[blockIdx.x] + (t > 0 ? s[t - 1] : 0);
    if (base + 0 < N) pos[base + 0] = run; run += v0;
    if (base + 1 < N) pos[base + 1] = run; run += v1;
    if (base + 2 < N) pos[base + 2] = run; run += v2;
    if (base + 3 < N) pos[base + 3] = run;
}

// ===========================================================================
// One-time CSR permutation of the edge list: sd_csr[p]=(src,dst),
// eah_csr[p]=fp16(edge_attr).  24 B/edge scatter replaces the 2x 32 B/edge
// m2h scatters of the old pipeline.
// ===========================================================================
__global__ __launch_bounds__(256) void csr_scatter(
    const int* __restrict__ ei, const float* __restrict__ ea,
    const int* __restrict__ pos, const unsigned short* __restrict__ r,
    int2* __restrict__ sd, _Float16* __restrict__ eahc, int E)
{
    int e = blockIdx.x * 256 + threadIdx.x;
    if (e >= E) return;
    int s = ei[e];
    int d = ei[E + e];
    int p = pos[(size_t)s * NBKT + ((e >> 8) & (NBKT - 1))] + (int)r[e];
    float4 a0 = *(const float4*)(ea + (size_t)e * 8);
    float4 a1 = *(const float4*)(ea + (size_t)e * 8 + 4);
    half8 h;
    h[0] = (_Float16)a0.x; h[1] = (_Float16)a0.y;
    h[2] = (_Float16)a0.z; h[3] = (_Float16)a0.w;
    h[4] = (_Float16)a1.x; h[5] = (_Float16)a1.y;
    h[6] = (_Float16)a1.z; h[7] = (_Float16)a1.w;
    sd[p] = make_int2(s, d);
    *(half8*)(eahc + (size_t)p * 8) = h;
}

// ===========================================================================
// MFMA edge-MLP + in-kernel segmented max.  Block = 256 CSR-consecutive
// edges = 4 waves x one 16x16-tile-quad.  Layer-2 outputs are clamped >=0
// and max-reduced into LDS lmax[span][16] (int-compare == float-compare for
// non-negative floats), then combined into global agg[N,16] with atomicMax.
// Empty nodes stay at memset 0 == PyG fill.  No m2h materialization.
//   16x16x32 layouts: A[m=lane&15][k=8q+j], B[k=8q+j][n=lane&15],
//   C/D: col=lane&15, row=4q+reg.
// ===========================================================================
__global__ __launch_bounds__(256) void edge_mlp1_agg(
    const float* __restrict__ x,          // [N,4]
    const int2*  __restrict__ sd,         // [E] CSR (src,dst)
    const _Float16* __restrict__ eahc,    // [E,8] CSR fp16
    const float* __restrict__ w1, const float* __restrict__ b1,  // 16x16
    const float* __restrict__ w2, const float* __restrict__ b2,  // 16x16
    float* __restrict__ agg,              // [N,16] fp32, memset 0
    int E)
{
    __shared__ _Float16 itm[4][4][16][24];
    __shared__ int lmax[SPAN * 16];
    int tid = threadIdx.x;
    int w = tid >> 6, lane = tid & 63;
    int e16 = lane & 15, q = lane >> 4;
    int kbase = blockIdx.x * 256;
    int ebase = kbase + (w << 6);
    int e = ebase + lane;
    bool bvalid = kbase < E;

    #pragma unroll
    for (int i = 0; i < SPAN * 16 / 256; ++i) lmax[tid + i * 256] = 0;

    int n_first = 0, span = 0;
    bool fb = false;
    if (bvalid) {
        int klast = min(kbase + 255, E - 1);
        n_first = sd[kbase].x;
        int n_last = sd[klast].x;
        span = n_last - n_first + 1;
        fb = (span > SPAN);
    }
    __syncthreads();

    int s_l = 0, d_l = 0;
    if (e < E) { int2 p = sd[e]; s_l = p.x; d_l = p.y; }

    half8 B1, B2;
    #pragma unroll
    for (int j = 0; j < 8; ++j) { B1[j] = (_Float16)0.f; B2[j] = (_Float16)0.f; }
    if (q < 2) {
        #pragma unroll
        for (int j = 0; j < 8; ++j) {
            B1[j] = (_Float16)w1[(8 * q + j) * 16 + e16];
            B2[j] = (_Float16)w2[(8 * q + j) * 16 + e16];
        }
    }
    float b1c = b1[e16], b2c = b2[e16];

    half8 A[4];
    #pragma unroll
    for (int t = 0; t < 4; ++t) {
        int st = __shfl(s_l, 16 * t + e16, 64);
        int dt = __shfl(d_l, 16 * t + e16, 64);
        half8 a;
        #pragma unroll
        for (int j = 0; j < 8; ++j) a[j] = (_Float16)0.f;
        int et = ebase + 16 * t + e16;
        if (q == 0 && et < E) {
            float4 xs = *(const float4*)(x + (size_t)st * 4);
            float4 xd = *(const float4*)(x + (size_t)dt * 4);
            a[0] = (_Float16)xs.x; a[1] = (_Float16)xs.y;
            a[2] = (_Float16)xs.z; a[3] = (_Float16)xs.w;
            a[4] = (_Float16)xd.x; a[5] = (_Float16)xd.y;
            a[6] = (_Float16)xd.z; a[7] = (_Float16)xd.w;
        } else if (q == 1 && et < E) {
            a = *(const half8*)(eahc + (size_t)et * 8);
        }
        A[t] = a;
    }

    floatx4 C[4];
    #pragma unroll
    for (int t = 0; t < 4; ++t) {
        floatx4 c = {b1c, b1c, b1c, b1c};
        C[t] = __builtin_amdgcn_mfma_f32_16x16x32_f16(A[t], B1, c, 0, 0, 0);
    }
    #pragma unroll
    for (int t = 0; t < 4; ++t)
        #pragma unroll
        for (int i = 0; i < 4; ++i)
            itm[w][t][4 * q + i][e16] = (_Float16)fmaxf(C[t][i], 0.0f);
    __builtin_amdgcn_wave_barrier();

    half8 A2[4];
    #pragma unroll
    for (int t = 0; t < 4; ++t) {
        half8 a;
        #pragma unroll
        for (int j = 0; j < 8; ++j) a[j] = (_Float16)0.f;
        if (q < 2) a = *(const half8*)&itm[w][t][e16][8 * q];
        A2[t] = a;
    }
    __builtin_amdgcn_wave_barrier();
    floatx4 C2[4];
    #pragma unroll
    for (int t = 0; t < 4; ++t) {
        floatx4 c = {b2c, b2c, b2c, b2c};
        C2[t] = __builtin_amdgcn_mfma_f32_16x16x32_f16(A2[t], B2, c, 0, 0, 0);
    }

    // segmented max: lane holds channel e16 of edges ebase+16t+4q+i
    int* agg_i = (int*)agg;
    #pragma unroll
    for (int t = 0; t < 4; ++t) {
        #pragma unroll
        for (int i = 0; i < 4; ++i) {
            int li = 16 * t + 4 * q + i;
            int nn = __shfl(s_l, li, 64);
            int et = ebase + li;
            if (et < E) {
                int bits = __float_as_int(fmaxf(C2[t][i], 0.0f));
                if (!fb) atomicMax(&lmax[(nn - n_first) * 16 + e16], bits);
                else     atomicMax(&agg_i[(size_t)nn * 16 + e16], bits);
            }
        }
    }
    __syncthreads();
    if (bvalid && !fb) {
        int tot = span * 16;
        for (int idx = tid; idx < tot; idx += 256) {
            int v = lmax[idx];
            if (v != 0)
                atomicMax(&agg_i[(size_t)(n_first + (idx >> 4)) * 16 + (idx & 15)], v);
        }
    }
}

__global__ __launch_bounds__(256) void edge_mlp2_agg(
    const float* __restrict__ hw_s,            // [N,16] fp32 (cb1 folded)
    const unsigned short* __restrict__ hw_dh,  // [N,16] fp16
    const int2*  __restrict__ sd,
    const _Float16* __restrict__ eahc,
    const float* __restrict__ w1,              // [40,16] rows 32:40 used
    const float* __restrict__ w2, const float* __restrict__ b2,
    float* __restrict__ agg, int E)
{
    __shared__ _Float16 itm[4][4][16][24];
    __shared__ int lmax[SPAN * 16];
    int tid = threadIdx.x;
    int w = tid >> 6, lane = tid & 63;
    int e16 = lane & 15, q = lane >> 4;
    const __half* hwd = (const __half*)hw_dh;
    int kbase = blockIdx.x * 256;
    int ebase = kbase + (w << 6);
    int e = ebase + lane;
    bool bvalid = kbase < E;

    #pragma unroll
    for (int i = 0; i < SPAN * 16 / 256; ++i) lmax[tid + i * 256] = 0;

    int n_first = 0, span = 0;
    bool fb = false;
    if (bvalid) {
        int klast = min(kbase + 255, E - 1);
        n_first = sd[kbase].x;
        int n_last = sd[klast].x;
        span = n_last - n_first + 1;
        fb = (span > SPAN);
    }
    __syncthreads();

    int s_l = 0, d_l = 0;
    if (e < E) { int2 p = sd[e]; s_l = p.x; d_l = p.y; }

    half8 B1, B2;
    #pragma unroll
    for (int j = 0; j < 8; ++j) { B1[j] = (_Float16)0.f; B2[j] = (_Float16)0.f; }
    if (q == 0) {
        #pragma unroll
        for (int j = 0; j < 8; ++j)
            B1[j] = (_Float16)w1[(32 + j) * 16 + e16];
    }
    if (q < 2) {
        #pragma unroll
        for (int j = 0; j < 8; ++j)
            B2[j] = (_Float16)w2[(8 * q + j) * 16 + e16];
    }
    float b2c = b2[e16];

    half8 A[4];
    #pragma unroll
    for (int t = 0; t < 4; ++t) {
        half8 a;
        #pragma unroll
        for (int j = 0; j < 8; ++j) a[j] = (_Float16)0.f;
        int et = ebase + 16 * t + e16;
        if (q == 0 && et < E)
            a = *(const half8*)(eahc + (size_t)et * 8);
        A[t] = a;
    }

    int sv[4][4];
    floatx4 C[4];
    #pragma unroll
    for (int t = 0; t < 4; ++t) {
        floatx4 c;
        #pragma unroll
        for (int i = 0; i < 4; ++i) {
            int li = 16 * t + 4 * q + i;
            int s = __shfl(s_l, li, 64);
            int d = __shfl(d_l, li, 64);
            sv[t][i] = s;
            int rr = ebase + li;
            float v = 0.0f;
            if (rr < E) {
                v = hw_s[(size_t)s * 16 + e16]
                  + __half2float(hwd[(size_t)d * 16 + e16]);
            }
            c[i] = v;
        }
        C[t] = __builtin_amdgcn_mfma_f32_16x16x32_f16(A[t], B1, c, 0, 0, 0);
    }
    #pragma unroll
    for (int t = 0; t < 4; ++t)
        #pragma unroll
        for (int i = 0; i < 4; ++i)
            itm[w][t][4 * q + i][e16] = (_Float16)fmaxf(C[t][i], 0.0f);
    __builtin_amdgcn_wave_barrier();

    half8 A2[4];
    #pragma unroll
    for (int t = 0; t < 4; ++t) {
        half8 a;
        #pragma unroll
        for (int j = 0; j < 8; ++j) a[j] = (_Float16)0.f;
        if (q < 2) a = *(const half8*)&itm[w][t][e16][8 * q];
        A2[t] = a;
    }
    __builtin_amdgcn_wave_barrier();
    floatx4 C2[4];
    #pragma unroll
    for (int t = 0; t < 4; ++t) {
        floatx4 c = {b2c, b2c, b2c, b2c};
        C2[t] = __builtin_amdgcn_mfma_f32_16x16x32_f16(A2[t], B2, c, 0, 0, 0);
    }

    int* agg_i = (int*)agg;
    #pragma unroll
    for (int t = 0; t < 4; ++t) {
        #pragma unroll
        for (int i = 0; i < 4; ++i) {
            int li = 16 * t + 4 * q + i;
            int et = ebase + li;
            if (et < E) {
                int nn = sv[t][i];
                int bits = __float_as_int(fmaxf(C2[t][i], 0.0f));
                if (!fb) atomicMax(&lmax[(nn - n_first) * 16 + e16], bits);
                else     atomicMax(&agg_i[(size_t)nn * 16 + e16], bits);
            }
        }
    }
    __syncthreads();
    if (bvalid && !fb) {
        int tot = span * 16;
        for (int idx = tid; idx < tot; idx += 256) {
            int v = lmax[idx];
            if (v != 0)
                atomicMax(&agg_i[(size_t)(n_first + (idx >> 4)) * 16 + (idx & 15)], v);
        }
    }
}

// ===========================================================================
// Dense per-node epilogues (replace the streaming segmax kernels).
// ===========================================================================
__global__ __launch_bounds__(256) void hw_compute(
    const float* __restrict__ agg,
    const float* __restrict__ cw1, const float* __restrict__ cb1,
    float* __restrict__ hw_s, unsigned short* __restrict__ hw_dh, int N)
{
    int tid = threadIdx.x;
    int n = blockIdx.x * 32 + (tid >> 3);
    if (n >= N) return;
    int g = tid & 7;
    const float4* ar = (const float4*)(agg + (size_t)n * 16);
    float4 A0 = ar[0], A1 = ar[1], A2 = ar[2], A3 = ar[3];
    float acc[16] = {A0.x, A0.y, A0.z, A0.w, A1.x, A1.y, A1.z, A1.w,
                     A2.x, A2.y, A2.z, A2.w, A3.x, A3.y, A3.z, A3.w};
    int j0 = 2 * g, j1 = 2 * g + 1;
    float hs0 = cb1[j0], hs1 = cb1[j1], hd0 = 0.0f, hd1 = 0.0f;
    #pragma unroll
    for (int k = 0; k < 16; ++k) {
        float ak = acc[k];
        hs0 = fmaf(ak, cw1[k * 16 + j0], hs0);
        hs1 = fmaf(ak, cw1[k * 16 + j1], hs1);
        hd0 = fmaf(ak, cw1[(16 + k) * 16 + j0], hd0);
        hd1 = fmaf(ak, cw1[(16 + k) * 16 + j1], hd1);
    }
    *(float2*)(hw_s + (size_t)n * 16 + j0) = make_float2(hs0, hs1);
    ((unsigned int*)hw_dh)[(size_t)n * 8 + g] = pack2(hd0, hd1);
}

__global__ __launch_bounds__(256) void head_out(
    const float* __restrict__ agg,
    const float* __restrict__ l1w, const float* __restrict__ l1b,
    const float* __restrict__ l2w, const float* __restrict__ l2b,
    float* __restrict__ out, int N)
{
    int n = blockIdx.x * 256 + threadIdx.x;
    if (n >= N) return;
    const float4* ar = (const float4*)(agg + (size_t)n * 16);
    float4 A0 = ar[0], A1 = ar[1], A2 = ar[2], A3 = ar[3];
    float acc[16] = {A0.x, A0.y, A0.z, A0.w, A1.x, A1.y, A1.z, A1.w,
                     A2.x, A2.y, A2.z, A2.w, A3.x, A3.y, A3.z, A3.w};
    float t2[16];
    #pragma unroll
    for (int j = 0; j < 16; ++j) t2[j] = l1b[j];
    #pragma unroll
    for (int k = 0; k < 16; ++k) {
        float ak = acc[k];
        #pragma unroll
        for (int j = 0; j < 16; ++j) t2[j] = fmaf(ak, l1w[k * 16 + j], t2[j]);
    }
    float r2 = l2b[0];
    #pragma unroll
    for (int j = 0; j < 16; ++j) r2 = fmaf(fmaxf(t2[j], 0.0f), l2w[j], r2);
    out[n] = r2;
}

// ===========================================================================
extern "C" void kernel_launch(void* const* d_in, const int* in_sizes, int n_in,
                              void* d_out, int out_size, void* d_ws, size_t ws_size,
                              hipStream_t stream)
{
    const float* x     = (const float*)d_in[0];
    const int*   ei    = (const int*)  d_in[1];
    const float* ea    = (const float*)d_in[2];
    const float* c1_w1 = (const float*)d_in[3];
    const float* c1_b1 = (const float*)d_in[4];
    const float* c1_w2 = (const float*)d_in[5];
    const float* c1_b2 = (const float*)d_in[6];
    const float* c2_w1 = (const float*)d_in[7];
    const float* c2_b1 = (const float*)d_in[8];
    const float* c2_w2 = (const float*)d_in[9];
    const float* c2_b2 = (const float*)d_in[10];
    const float* l1_w  = (const float*)d_in[11];
    const float* l1_b  = (const float*)d_in[12];
    const float* l2_w  = (const float*)d_in[13];
    const float* l2_b  = (const float*)d_in[14];
    float* out = (float*)d_out;

    const int N = in_sizes[0] / 4;   // 100000
    const int E = in_sizes[2] / 8;   // 1600000
    const int M = N * NBKT;
    const int nch = (M + CHUNK - 1) / CHUNK;

    const int BLK = 256;
    const int egrid = (E + BLK - 1) / BLK;
    const int ggrid = (N + 31) / 32;
    const int ngrid = (N + 255) / 256;
    const int mgrid = (E + 255) / 256;   // 256 CSR edges per block

    size_t szPos  = ((size_t)M * 4 + 15) & ~(size_t)15;   // 3.2 MB
    size_t szEh   = ((size_t)E * 2 + 15) & ~(size_t)15;   // 3.2 MB (r)
    size_t szSd   = (size_t)E * 8;                        // 12.8 MB
    size_t szEah  = (size_t)E * 16;                       // 25.6 MB
    size_t szAgg  = (size_t)N * 16 * 4;                   // 6.4 MB
    size_t szHws  = (size_t)N * 16 * 4;                   // 6.4 MB
    size_t szHwd  = (size_t)N * 16 * 2;                   // 3.2 MB

    size_t pos_off  = 0;
    size_t r_off    = pos_off  + szPos;
    size_t sd_off   = r_off    + szEh;
    size_t eah_off  = sd_off   + szSd;
    size_t agg_off  = eah_off  + szEah;
    size_t hws_off  = agg_off  + szAgg;
    size_t hwdh_off = hws_off  + szHws;
    // overlays inside agg (dead before first agg memset):
    size_t deg_off  = agg_off;
    size_t cs_off   = deg_off  + szPos;
    size_t cf_off   = cs_off   + 16384;

    int*            pos  = (int*)  ((char*)d_ws + pos_off);
    unsigned short* r    = (unsigned short*)((char*)d_ws + r_off);
    int2*           sd   = (int2*) ((char*)d_ws + sd_off);
    _Float16*       eahc = (_Float16*)((char*)d_ws + eah_off);
    float*          agg  = (float*)((char*)d_ws + agg_off);
    float*          hw_s = (float*)((char*)d_ws + hws_off);
    unsigned short* hwdh = (unsigned short*)((char*)d_ws + hwdh_off);
    int*            deg  = (int*)  ((char*)d_ws + deg_off);
    int*            csum = (int*)  ((char*)d_ws + cs_off);
    int*            coff = (int*)  ((char*)d_ws + cf_off);

    hipMemsetAsync(deg, 0, (size_t)M * 4, stream);
    rank_cvt<<<egrid, BLK, 0, stream>>>(ei, deg, r, E);
    scan_chunk_sums<<<nch, BLK, 0, stream>>>(deg, csum, M);
    scan_chunk_off<<<1, 256, 0, stream>>>(csum, coff, nch);
    scan_within_excl<<<nch, BLK, 0, stream>>>(deg, pos, coff, M);
    // deg/csum/coff dead from here; agg overlays them
    hipMemsetAsync(agg, 0, szAgg, stream);
    csr_scatter<<<egrid, BLK, 0, stream>>>(ei, ea, pos, r, sd, eahc, E);
    edge_mlp1_agg<<<mgrid, BLK, 0, stream>>>(x, sd, eahc,
                                             c1_w1, c1_b1, c1_w2, c1_b2,
                                             agg, E);
    hw_compute<<<ggrid, BLK, 0, stream>>>(agg, c2_w1, c2_b1, hw_s, hwdh, N);
    hipMemsetAsync(agg, 0, szAgg, stream);
    edge_mlp2_agg<<<mgrid, BLK, 0, stream>>>(hw_s, hwdh, sd, eahc,
                                             c2_w1, c2_w2, c2_b2, agg, E);
    head_out<<<ngrid, BLK, 0, stream>>>(agg, l1_w, l1_b, l2_w, l2_b, out, N);
}

// Round 4
// 380.675 us; speedup vs baseline: 1.0088x; 1.0088x over previous
//
#include <hip/hip_runtime.h>
#include <hip/hip_fp16.h>

#define CHUNK 1024
#define NBKT 8     // per-node atomic-counter buckets
#define SPAN 128   // max node-span of a 256-edge CSR chunk handled in LDS
#define RECB 24    // bytes per CSR record: {int src, int dst, 8x fp16 attr}

typedef _Float16 half8 __attribute__((ext_vector_type(8)));
typedef float floatx4 __attribute__((ext_vector_type(4)));

__device__ __forceinline__ unsigned int pack2(float a, float b) {
    __half2 h = __floats2half2_rn(a, b);
    return *(unsigned int*)&h;
}

// ===========================================================================
// degree count (src-only read)
// ===========================================================================
__global__ __launch_bounds__(256) void count_deg(
    const int* __restrict__ ei, int* __restrict__ deg, int E)
{
    int e = blockIdx.x * 256 + threadIdx.x;
    if (e >= E) return;
    atomicAdd(&deg[(size_t)ei[e] * NBKT + ((e >> 8) & (NBKT - 1))], 1);
}

__global__ __launch_bounds__(256) void scan_chunk_sums(
    const int* __restrict__ v, int* __restrict__ csum, int N)
{
    __shared__ int s[256];
    int base = blockIdx.x * CHUNK;
    int t = threadIdx.x;
    int acc = 0;
    #pragma unroll
    for (int i = 0; i < CHUNK / 256; ++i) {
        int idx = base + t + i * 256;
        if (idx < N) acc += v[idx];
    }
    s[t] = acc; __syncthreads();
    for (int o = 128; o > 0; o >>= 1) {
        if (t < o) s[t] += s[t + o];
        __syncthreads();
    }
    if (t == 0) csum[blockIdx.x] = s[0];
}

__global__ __launch_bounds__(256) void scan_chunk_off(
    const int* __restrict__ csum, int* __restrict__ coff, int nch)
{
    __shared__ int s[256];
    __shared__ int carry;
    int t = threadIdx.x;
    if (t == 0) carry = 0;
    __syncthreads();
    for (int base = 0; base < nch; base += 256) {
        int v = (base + t < nch) ? csum[base + t] : 0;
        s[t] = v; __syncthreads();
        for (int o = 1; o < 256; o <<= 1) {
            int add = (t >= o) ? s[t - o] : 0;
            __syncthreads();
            s[t] += add;
            __syncthreads();
        }
        int excl = carry + (t > 0 ? s[t - 1] : 0);
        if (base + t < nch) coff[base + t] = excl;
        __syncthreads();
        if (t == 0) carry += s[255];
        __syncthreads();
    }
}

// writes the exclusive scan DIRECTLY into the cursor array consumed by
// scatter_rank's atomicAdd (cursor == running CSR slot per (node,bucket))
__global__ __launch_bounds__(256) void scan_within_excl(
    const int* __restrict__ deg, int* __restrict__ pos,
    const int* __restrict__ coff, int N)
{
    __shared__ int s[256];
    int t = threadIdx.x;
    int base = blockIdx.x * CHUNK + t * 4;
    int v0 = 0, v1 = 0, v2 = 0, v3 = 0;
    if (base + 0 < N) v0 = deg[base + 0];
    if (base + 1 < N) v1 = deg[base + 1];
    if (base + 2 < N) v2 = deg[base + 2];
    if (base + 3 < N) v3 = deg[base + 3];
    s[t] = v0 + v1 + v2 + v3;
    __syncthreads();
    for (int o = 1; o < 256; o <<= 1) {
        int add = (t >= o) ? s[t - o] : 0;
        __syncthreads();
        s[t] += add;
        __syncthreads();
    }
    int run = coff[blockIdx.x] + (t > 0 ? s[t - 1] : 0);
    if (base + 0 < N) pos[base + 0] = run; run += v0;
    if (base + 1 < N) pos[base + 1] = run; run += v1;
    if (base + 2 < N) pos[base + 2] = run; run += v2;
    if (base + 3 < N) pos[base + 3] = run;
}

// ===========================================================================
// Fused rank + CSR scatter: the cursor atomicAdd IS the pos lookup AND the
// rank assignment.  Writes one packed 24 B record per edge
// (~2.7 writers/64B line vs 8-and-4 for split arrays).
// ===========================================================================
__global__ __launch_bounds__(256) void scatter_rank(
    const int* __restrict__ ei, const float* __restrict__ ea,
    int* __restrict__ cursor, char* __restrict__ rec, int E)
{
    int e = blockIdx.x * 256 + threadIdx.x;
    if (e >= E) return;
    int s = ei[e];
    int d = ei[E + e];
    int p = atomicAdd(&cursor[(size_t)s * NBKT + ((e >> 8) & (NBKT - 1))], 1);
    float4 a0 = *(const float4*)(ea + (size_t)e * 8);
    float4 a1 = *(const float4*)(ea + (size_t)e * 8 + 4);
    unsigned int h0 = pack2(a0.x, a0.y), h1 = pack2(a0.z, a0.w);
    unsigned int h2 = pack2(a1.x, a1.y), h3 = pack2(a1.z, a1.w);
    char* b = rec + (size_t)p * RECB;
    *(int2*)b          = make_int2(s, d);
    *(uint2*)(b + 8)   = make_uint2(h0, h1);
    *(uint2*)(b + 16)  = make_uint2(h2, h3);
}

__device__ __forceinline__ half8 load_attr(const char* __restrict__ rec, int et) {
    union { unsigned int u[4]; half8 h; } cv;
    uint2 lo = *(const uint2*)(rec + (size_t)et * RECB + 8);
    uint2 hi = *(const uint2*)(rec + (size_t)et * RECB + 16);
    cv.u[0] = lo.x; cv.u[1] = lo.y; cv.u[2] = hi.x; cv.u[3] = hi.y;
    return cv.h;
}

// ===========================================================================
// MFMA edge-MLP + in-kernel segmented max.  Block = 256 CSR-consecutive
// edges = 4 waves x one 16x16-tile-quad.  Layer-2 outputs clamped >=0,
// max-reduced in LDS lmax[span][16] (int-compare == float-compare for
// non-negative floats), then one global atomicMax per touched (node,ch).
//   16x16x32 layouts: A[m=lane&15][k=8q+j], B[k=8q+j][n=lane&15],
//   C/D: col=lane&15, row=4q+reg.
// ===========================================================================
__global__ __launch_bounds__(256) void edge_mlp1_agg(
    const float* __restrict__ x,          // [N,4]
    const char*  __restrict__ rec,        // [E] 24B CSR records
    const float* __restrict__ w1, const float* __restrict__ b1,  // 16x16
    const float* __restrict__ w2, const float* __restrict__ b2,  // 16x16
    float* __restrict__ agg,              // [N,16] fp32, memset 0
    int E)
{
    __shared__ _Float16 itm[4][4][16][24];
    __shared__ int lmax[SPAN * 16];
    int tid = threadIdx.x;
    int w = tid >> 6, lane = tid & 63;
    int e16 = lane & 15, q = lane >> 4;
    int kbase = blockIdx.x * 256;
    int ebase = kbase + (w << 6);
    int e = ebase + lane;
    bool bvalid = kbase < E;

    #pragma unroll
    for (int i = 0; i < SPAN * 16 / 256; ++i) lmax[tid + i * 256] = 0;

    int n_first = 0, span = 0;
    bool fb = false;
    if (bvalid) {
        int klast = min(kbase + 255, E - 1);
        n_first = *(const int*)(rec + (size_t)kbase * RECB);
        int n_last = *(const int*)(rec + (size_t)klast * RECB);
        span = n_last - n_first + 1;
        fb = (span > SPAN);
    }
    __syncthreads();

    int s_l = 0, d_l = 0;
    if (e < E) { int2 p = *(const int2*)(rec + (size_t)e * RECB); s_l = p.x; d_l = p.y; }

    half8 B1, B2;
    #pragma unroll
    for (int j = 0; j < 8; ++j) { B1[j] = (_Float16)0.f; B2[j] = (_Float16)0.f; }
    if (q < 2) {
        #pragma unroll
        for (int j = 0; j < 8; ++j) {
            B1[j] = (_Float16)w1[(8 * q + j) * 16 + e16];
            B2[j] = (_Float16)w2[(8 * q + j) * 16 + e16];
        }
    }
    float b1c = b1[e16], b2c = b2[e16];

    half8 A[4];
    #pragma unroll
    for (int t = 0; t < 4; ++t) {
        int st = __shfl(s_l, 16 * t + e16, 64);
        int dt = __shfl(d_l, 16 * t + e16, 64);
        half8 a;
        #pragma unroll
        for (int j = 0; j < 8; ++j) a[j] = (_Float16)0.f;
        int et = ebase + 16 * t + e16;
        if (q == 0 && et < E) {
            float4 xs = *(const float4*)(x + (size_t)st * 4);
            float4 xd = *(const float4*)(x + (size_t)dt * 4);
            a[0] = (_Float16)xs.x; a[1] = (_Float16)xs.y;
            a[2] = (_Float16)xs.z; a[3] = (_Float16)xs.w;
            a[4] = (_Float16)xd.x; a[5] = (_Float16)xd.y;
            a[6] = (_Float16)xd.z; a[7] = (_Float16)xd.w;
        } else if (q == 1 && et < E) {
            a = load_attr(rec, et);
        }
        A[t] = a;
    }

    floatx4 C[4];
    #pragma unroll
    for (int t = 0; t < 4; ++t) {
        floatx4 c = {b1c, b1c, b1c, b1c};
        C[t] = __builtin_amdgcn_mfma_f32_16x16x32_f16(A[t], B1, c, 0, 0, 0);
    }
    #pragma unroll
    for (int t = 0; t < 4; ++t)
        #pragma unroll
        for (int i = 0; i < 4; ++i)
            itm[w][t][4 * q + i][e16] = (_Float16)fmaxf(C[t][i], 0.0f);
    __builtin_amdgcn_wave_barrier();

    half8 A2[4];
    #pragma unroll
    for (int t = 0; t < 4; ++t) {
        half8 a;
        #pragma unroll
        for (int j = 0; j < 8; ++j) a[j] = (_Float16)0.f;
        if (q < 2) a = *(const half8*)&itm[w][t][e16][8 * q];
        A2[t] = a;
    }
    __builtin_amdgcn_wave_barrier();
    floatx4 C2[4];
    #pragma unroll
    for (int t = 0; t < 4; ++t) {
        floatx4 c = {b2c, b2c, b2c, b2c};
        C2[t] = __builtin_amdgcn_mfma_f32_16x16x32_f16(A2[t], B2, c, 0, 0, 0);
    }

    int* agg_i = (int*)agg;
    #pragma unroll
    for (int t = 0; t < 4; ++t) {
        #pragma unroll
        for (int i = 0; i < 4; ++i) {
            int li = 16 * t + 4 * q + i;
            int nn = __shfl(s_l, li, 64);
            int et = ebase + li;
            if (et < E) {
                int bits = __float_as_int(fmaxf(C2[t][i], 0.0f));
                if (!fb) atomicMax(&lmax[(nn - n_first) * 16 + e16], bits);
                else     atomicMax(&agg_i[(size_t)nn * 16 + e16], bits);
            }
        }
    }
    __syncthreads();
    if (bvalid && !fb) {
        int tot = span * 16;
        for (int idx = tid; idx < tot; idx += 256) {
            int v = lmax[idx];
            if (v != 0)
                atomicMax(&agg_i[(size_t)(n_first + (idx >> 4)) * 16 + (idx & 15)], v);
        }
    }
}

__global__ __launch_bounds__(256) void edge_mlp2_agg(
    const float* __restrict__ hw_s,            // [N,16] fp32 (cb1 folded)
    const unsigned short* __restrict__ hw_dh,  // [N,16] fp16
    const char*  __restrict__ rec,
    const float* __restrict__ w1,              // [40,16] rows 32:40 used
    const float* __restrict__ w2, const float* __restrict__ b2,
    float* __restrict__ agg, int E)
{
    __shared__ _Float16 itm[4][4][16][24];
    __shared__ int lmax[SPAN * 16];
    int tid = threadIdx.x;
    int w = tid >> 6, lane = tid & 63;
    int e16 = lane & 15, q = lane >> 4;
    const __half* hwd = (const __half*)hw_dh;
    int kbase = blockIdx.x * 256;
    int ebase = kbase + (w << 6);
    int e = ebase + lane;
    bool bvalid = kbase < E;

    #pragma unroll
    for (int i = 0; i < SPAN * 16 / 256; ++i) lmax[tid + i * 256] = 0;

    int n_first = 0, span = 0;
    bool fb = false;
    if (bvalid) {
        int klast = min(kbase + 255, E - 1);
        n_first = *(const int*)(rec + (size_t)kbase * RECB);
        int n_last = *(const int*)(rec + (size_t)klast * RECB);
        span = n_last - n_first + 1;
        fb = (span > SPAN);
    }
    __syncthreads();

    int s_l = 0, d_l = 0;
    if (e < E) { int2 p = *(const int2*)(rec + (size_t)e * RECB); s_l = p.x; d_l = p.y; }

    half8 B1, B2;
    #pragma unroll
    for (int j = 0; j < 8; ++j) { B1[j] = (_Float16)0.f; B2[j] = (_Float16)0.f; }
    if (q == 0) {
        #pragma unroll
        for (int j = 0; j < 8; ++j)
            B1[j] = (_Float16)w1[(32 + j) * 16 + e16];
    }
    if (q < 2) {
        #pragma unroll
        for (int j = 0; j < 8; ++j)
            B2[j] = (_Float16)w2[(8 * q + j) * 16 + e16];
    }
    float b2c = b2[e16];

    half8 A[4];
    #pragma unroll
    for (int t = 0; t < 4; ++t) {
        half8 a;
        #pragma unroll
        for (int j = 0; j < 8; ++j) a[j] = (_Float16)0.f;
        int et = ebase + 16 * t + e16;
        if (q == 0 && et < E)
            a = load_attr(rec, et);
        A[t] = a;
    }

    int sv[4][4];
    floatx4 C[4];
    #pragma unroll
    for (int t = 0; t < 4; ++t) {
        floatx4 c;
        #pragma unroll
        for (int i = 0; i < 4; ++i) {
            int li = 16 * t + 4 * q + i;
            int s = __shfl(s_l, li, 64);
            int d = __shfl(d_l, li, 64);
            sv[t][i] = s;
            int rr = ebase + li;
            float v = 0.0f;
            if (rr < E) {
                v = hw_s[(size_t)s * 16 + e16]
                  + __half2float(hwd[(size_t)d * 16 + e16]);
            }
            c[i] = v;
        }
        C[t] = __builtin_amdgcn_mfma_f32_16x16x32_f16(A[t], B1, c, 0, 0, 0);
    }
    #pragma unroll
    for (int t = 0; t < 4; ++t)
        #pragma unroll
        for (int i = 0; i < 4; ++i)
            itm[w][t][4 * q + i][e16] = (_Float16)fmaxf(C[t][i], 0.0f);
    __builtin_amdgcn_wave_barrier();

    half8 A2[4];
    #pragma unroll
    for (int t = 0; t < 4; ++t) {
        half8 a;
        #pragma unroll
        for (int j = 0; j < 8; ++j) a[j] = (_Float16)0.f;
        if (q < 2) a = *(const half8*)&itm[w][t][e16][8 * q];
        A2[t] = a;
    }
    __builtin_amdgcn_wave_barrier();
    floatx4 C2[4];
    #pragma unroll
    for (int t = 0; t < 4; ++t) {
        floatx4 c = {b2c, b2c, b2c, b2c};
        C2[t] = __builtin_amdgcn_mfma_f32_16x16x32_f16(A2[t], B2, c, 0, 0, 0);
    }

    int* agg_i = (int*)agg;
    #pragma unroll
    for (int t = 0; t < 4; ++t) {
        #pragma unroll
        for (int i = 0; i < 4; ++i) {
            int li = 16 * t + 4 * q + i;
            int et = ebase + li;
            if (et < E) {
                int nn = sv[t][i];
                int bits = __float_as_int(fmaxf(C2[t][i], 0.0f));
                if (!fb) atomicMax(&lmax[(nn - n_first) * 16 + e16], bits);
                else     atomicMax(&agg_i[(size_t)nn * 16 + e16], bits);
            }
        }
    }
    __syncthreads();
    if (bvalid && !fb) {
        int tot = span * 16;
        for (int idx = tid; idx < tot; idx += 256) {
            int v = lmax[idx];
            if (v != 0)
                atomicMax(&agg_i[(size_t)(n_first + (idx >> 4)) * 16 + (idx & 15)], v);
        }
    }
}

// ===========================================================================
// Dense per-node epilogues.
// ===========================================================================
__global__ __launch_bounds__(256) void hw_compute(
    const float* __restrict__ agg,
    const float* __restrict__ cw1, const float* __restrict__ cb1,
    float* __restrict__ hw_s, unsigned short* __restrict__ hw_dh, int N)
{
    int tid = threadIdx.x;
    int n = blockIdx.x * 32 + (tid >> 3);
    if (n >= N) return;
    int g = tid & 7;
    const float4* ar = (const float4*)(agg + (size_t)n * 16);
    float4 A0 = ar[0], A1 = ar[1], A2 = ar[2], A3 = ar[3];
    float acc[16] = {A0.x, A0.y, A0.z, A0.w, A1.x, A1.y, A1.z, A1.w,
                     A2.x, A2.y, A2.z, A2.w, A3.x, A3.y, A3.z, A3.w};
    int j0 = 2 * g, j1 = 2 * g + 1;
    float hs0 = cb1[j0], hs1 = cb1[j1], hd0 = 0.0f, hd1 = 0.0f;
    #pragma unroll
    for (int k = 0; k < 16; ++k) {
        float ak = acc[k];
        hs0 = fmaf(ak, cw1[k * 16 + j0], hs0);
        hs1 = fmaf(ak, cw1[k * 16 + j1], hs1);
        hd0 = fmaf(ak, cw1[(16 + k) * 16 + j0], hd0);
        hd1 = fmaf(ak, cw1[(16 + k) * 16 + j1], hd1);
    }
    *(float2*)(hw_s + (size_t)n * 16 + j0) = make_float2(hs0, hs1);
    ((unsigned int*)hw_dh)[(size_t)n * 8 + g] = pack2(hd0, hd1);
}

__global__ __launch_bounds__(256) void head_out(
    const float* __restrict__ agg,
    const float* __restrict__ l1w, const float* __restrict__ l1b,
    const float* __restrict__ l2w, const float* __restrict__ l2b,
    float* __restrict__ out, int N)
{
    int n = blockIdx.x * 256 + threadIdx.x;
    if (n >= N) return;
    const float4* ar = (const float4*)(agg + (size_t)n * 16);
    float4 A0 = ar[0], A1 = ar[1], A2 = ar[2], A3 = ar[3];
    float acc[16] = {A0.x, A0.y, A0.z, A0.w, A1.x, A1.y, A1.z, A1.w,
                     A2.x, A2.y, A2.z, A2.w, A3.x, A3.y, A3.z, A3.w};
    float t2[16];
    #pragma unroll
    for (int j = 0; j < 16; ++j) t2[j] = l1b[j];
    #pragma unroll
    for (int k = 0; k < 16; ++k) {
        float ak = acc[k];
        #pragma unroll
        for (int j = 0; j < 16; ++j) t2[j] = fmaf(ak, l1w[k * 16 + j], t2[j]);
    }
    float r2 = l2b[0];
    #pragma unroll
    for (int j = 0; j < 16; ++j) r2 = fmaf(fmaxf(t2[j], 0.0f), l2w[j], r2);
    out[n] = r2;
}

// ===========================================================================
extern "C" void kernel_launch(void* const* d_in, const int* in_sizes, int n_in,
                              void* d_out, int out_size, void* d_ws, size_t ws_size,
                              hipStream_t stream)
{
    const float* x     = (const float*)d_in[0];
    const int*   ei    = (const int*)  d_in[1];
    const float* ea    = (const float*)d_in[2];
    const float* c1_w1 = (const float*)d_in[3];
    const float* c1_b1 = (const float*)d_in[4];
    const float* c1_w2 = (const float*)d_in[5];
    const float* c1_b2 = (const float*)d_in[6];
    const float* c2_w1 = (const float*)d_in[7];
    const float* c2_b1 = (const float*)d_in[8];
    const float* c2_w2 = (const float*)d_in[9];
    const float* c2_b2 = (const float*)d_in[10];
    const float* l1_w  = (const float*)d_in[11];
    const float* l1_b  = (const float*)d_in[12];
    const float* l2_w  = (const float*)d_in[13];
    const float* l2_b  = (const float*)d_in[14];
    float* out = (float*)d_out;

    const int N = in_sizes[0] / 4;   // 100000
    const int E = in_sizes[2] / 8;   // 1600000
    const int M = N * NBKT;
    const int nch = (M + CHUNK - 1) / CHUNK;

    const int BLK = 256;
    const int egrid = (E + BLK - 1) / BLK;
    const int ggrid = (N + 31) / 32;
    const int ngrid = (N + 255) / 256;
    const int mgrid = (E + 255) / 256;   // 256 CSR edges per block

    size_t szRec = (size_t)E * RECB;                      // 38.4 MB
    size_t szM   = ((size_t)M * 4 + 15) & ~(size_t)15;    // 3.2 MB
    size_t szAgg = (size_t)N * 16 * 4;                    // 6.4 MB
    size_t szHws = (size_t)N * 16 * 4;                    // 6.4 MB
    size_t szHwd = (size_t)N * 16 * 2;                    // 3.2 MB

    size_t rec_off  = 0;
    size_t agg_off  = rec_off + szRec;
    size_t hws_off  = agg_off + szAgg;
    size_t hwdh_off = hws_off + szHws;
    // overlays:
    size_t cur_off  = agg_off;            // cursor dead after scatter_rank
    size_t deg_off  = hws_off;            // deg dead after scans
    size_t cs_off   = hwdh_off;           // csum/coff dead after scans
    size_t cf_off   = cs_off + 4096;

    char*           rec  = (char*) ((char*)d_ws + rec_off);
    float*          agg  = (float*)((char*)d_ws + agg_off);
    float*          hw_s = (float*)((char*)d_ws + hws_off);
    unsigned short* hwdh = (unsigned short*)((char*)d_ws + hwdh_off);
    int*            cur  = (int*)  ((char*)d_ws + cur_off);
    int*            deg  = (int*)  ((char*)d_ws + deg_off);
    int*            csum = (int*)  ((char*)d_ws + cs_off);
    int*            coff = (int*)  ((char*)d_ws + cf_off);

    hipMemsetAsync(deg, 0, (size_t)M * 4, stream);
    count_deg<<<egrid, BLK, 0, stream>>>(ei, deg, E);
    scan_chunk_sums<<<nch, BLK, 0, stream>>>(deg, csum, M);
    scan_chunk_off<<<1, 256, 0, stream>>>(csum, coff, nch);
    scan_within_excl<<<nch, BLK, 0, stream>>>(deg, cur, coff, M);
    scatter_rank<<<egrid, BLK, 0, stream>>>(ei, ea, cur, rec, E);
    // cursor dead; agg overlays it
    hipMemsetAsync(agg, 0, szAgg, stream);
    edge_mlp1_agg<<<mgrid, BLK, 0, stream>>>(x, rec,
                                             c1_w1, c1_b1, c1_w2, c1_b2,
                                             agg, E);
    hw_compute<<<ggrid, BLK, 0, stream>>>(agg, c2_w1, c2_b1, hw_s, hwdh, N);
    hipMemsetAsync(agg, 0, szAgg, stream);
    edge_mlp2_agg<<<mgrid, BLK, 0, stream>>>(hw_s, hwdh, rec,
                                             c2_w1, c2_w2, c2_b2, agg, E);
    head_out<<<ngrid, BLK, 0, stream>>>(agg, l1_w, l1_b, l2_w, l2_b, out, N);
}